// Round 6
// baseline (333.659 us; speedup 1.0000x reference)
//
#include <hip/hip_runtime.h>

// Tree-RNN on MI355X — round 6: DIFFERENTIAL-TIMING PROBE.
// Pipeline is byte-identical to R5; the only change is that kernel_launch enqueues the
// whole (idempotent) pipeline TWICE. With R5: 249.1 = F + X and R6: D = F + 2X, the
// delta D - 249.1 isolates our controllable time X from the harness's fixed window cost
// (input restore + 536 MB ws re-poison), which saturates the rocprof top-5 and has made
// per-kernel attribution impossible. Second leaf pass also runs L3-warm on A, separating
// fetch-bound from latency-bound hypotheses.

typedef _Float16 half_t;
typedef __attribute__((ext_vector_type(8))) _Float16 half8;
typedef __attribute__((ext_vector_type(4))) float floatx4;

#define H0ROWS ((size_t)8192 * 112)

__device__ __forceinline__ void gld_lds16(const float* g, float* l) {
  __builtin_amdgcn_global_load_lds((const __attribute__((address_space(1))) void*)g,
                                   (__attribute__((address_space(3))) void*)l, 16, 0, 0);
}

__device__ __forceinline__ void cvt_hilo(const floatx4& a, const floatx4& b, half8& hi, half8& lo) {
#pragma unroll
  for (int j = 0; j < 4; ++j) {
    float v = a[j];
    half_t hh = (half_t)v;
    hi[j] = hh; lo[j] = (half_t)(v - (float)hh);
  }
#pragma unroll
  for (int j = 0; j < 4; ++j) {
    float v = b[j];
    half_t hh = (half_t)v;
    hi[4 + j] = hh; lo[4 + j] = (half_t)(v - (float)hh);
  }
}

// ---------------------------------------------------------------------------
// prep: blocks 0..199 convert We[100][4096] -> Bf fragments; blocks 200..212
// convert W[100][200] -> Wf fragments (K padded to 224, N to 112, zero-filled).
// ---------------------------------------------------------------------------
__global__ __launch_bounds__(256) void prep(const float* __restrict__ We,
                                            const float* __restrict__ W,
                                            half_t* __restrict__ Bf,
                                            half_t* __restrict__ Wf) {
  if (blockIdx.x < 200) {
    int t = blockIdx.x * 256 + threadIdx.x;  // 100 n x 512 kp
    int n = t >> 9;
    int kp = t & 511;
    int k0 = kp * 8;
    int ks = k0 >> 5;
    int q = (k0 >> 3) & 3;
    int c = n >> 4, m = n & 15;
    int lane = q * 16 + m;
    const float* src = We + (size_t)n * 4096 + k0;
    half8 hv, lv;
#pragma unroll
    for (int j = 0; j < 8; ++j) {
      float w = src[j];
      half_t hh = (half_t)w;
      hv[j] = hh; lv[j] = (half_t)(w - (float)hh);
    }
    size_t base = (size_t)(ks * 14 + c * 2) * 64 + lane;
    *(half8*)(Bf + base * 8) = hv;
    *(half8*)(Bf + (base + 64) * 8) = lv;
  } else {
    int u = (blockIdx.x - 200) * 256 + threadIdx.x;  // 49 frag-pairs x 64 lanes
    if (u >= 3136) return;
    int fb = u >> 6, lane = u & 63;
    int ks = fb / 7, tt = fb % 7;
    int q = lane >> 4, n = lane & 15;
    int col = tt * 16 + n;
    int kb = ks * 32 + q * 8;
    half8 hv, lv;
#pragma unroll
    for (int j = 0; j < 8; ++j) {
      int k = kb + j;
      float w = (col < 100 && k < 200) ? W[(size_t)col * 200 + k] : 0.f;
      half_t hh = (half_t)w;
      hv[j] = hh; lv[j] = (half_t)(w - (float)hh);
    }
    size_t base = (size_t)(ks * 14 + tt * 2) * 64 + lane;
    *(half8*)(Wf + base * 8) = hv;
    *(half8*)(Wf + (base + 64) * 8) = lv;
  }
}

// ---------------------------------------------------------------------------
// leaf_mfma: partial h0p[kh][row][col] = sum_{k in half kh} A[row][k]*We[col][k].
// 512 blocks x 256 thr (4 waves): block = (row-tile rt = b>>1) x (K-half kh = b&1).
// 8 chunks of BK=256, double-buffered LDS (2 blocks/CU). Waves split N.
// ---------------------------------------------------------------------------
__global__ __launch_bounds__(256, 2) void leaf_mfma(const float* __restrict__ A,
                                                    const half8* __restrict__ Bf,
                                                    float* __restrict__ h0p) {
  __shared__ __align__(16) float lds[2 * 8320];  // 2 bufs x 32 rows x 260 floats
  const int tid = threadIdx.x;
  const int lane = tid & 63;
  const int wave = tid >> 6;
  const int q = lane >> 4, m = lane & 15;
  const int rt = blockIdx.x >> 1;
  const int kh = blockIdx.x & 1;
  const int r0 = rt * 32;
  const int t0 = 2 * wave;
  const int t1 = (2 * wave + 1 < 7) ? (2 * wave + 1) : 6;
  const bool two = (t1 != t0);

  floatx4 acc[2][2];
#pragma unroll
  for (int a = 0; a < 2; ++a)
#pragma unroll
    for (int c = 0; c < 2; ++c) acc[a][c] = (floatx4){0.f, 0.f, 0.f, 0.f};

  const float* gbase = A + (size_t)(r0 + wave * 8) * 4096 + (size_t)kh * 2048 + lane * 4;
  const int ldso = (wave * 8) * 260 + lane * 4;

#pragma unroll
  for (int i = 0; i < 8; ++i) gld_lds16(gbase + (size_t)i * 4096, lds + ldso + i * 260);
  __syncthreads();

  for (int t = 0; t < 8; ++t) {
    half8 bh[8][2], bl[8][2];
    const int ksgb = kh * 64 + t * 8;
#pragma unroll
    for (int k = 0; k < 8; ++k) {
      const half8* bb = Bf + (size_t)((ksgb + k) * 14) * 64 + lane;
      bh[k][0] = bb[(t0 * 2) * 64];
      bl[k][0] = bb[(t0 * 2 + 1) * 64];
      if (two) {
        bh[k][1] = bb[(t1 * 2) * 64];
        bl[k][1] = bb[(t1 * 2 + 1) * 64];
      }
    }
    __builtin_amdgcn_sched_barrier(0);  // pin B loads before the staging instrs

    if (t < 7) {
      const float* g = gbase + (t + 1) * 256;
      float* d = lds + ((t + 1) & 1) * 8320 + ldso;
#pragma unroll
      for (int i = 0; i < 8; ++i) gld_lds16(g + (size_t)i * 4096, d + i * 260);
    }

    const float* cur = lds + (t & 1) * 8320;
#pragma unroll
    for (int k = 0; k < 8; ++k) {
      const float* ap = cur + m * 260 + k * 32 + q * 8;
      floatx4 a0 = *(const floatx4*)ap;
      floatx4 a1 = *(const floatx4*)(ap + 4);
      floatx4 a2 = *(const floatx4*)(ap + 16 * 260);
      floatx4 a3 = *(const floatx4*)(ap + 16 * 260 + 4);
      half8 ah0, al0, ah1, al1;
      cvt_hilo(a0, a1, ah0, al0);
      cvt_hilo(a2, a3, ah1, al1);
      acc[0][0] = __builtin_amdgcn_mfma_f32_16x16x32_f16(ah0, bh[k][0], acc[0][0], 0, 0, 0);
      acc[1][0] = __builtin_amdgcn_mfma_f32_16x16x32_f16(ah1, bh[k][0], acc[1][0], 0, 0, 0);
      acc[0][0] = __builtin_amdgcn_mfma_f32_16x16x32_f16(al0, bh[k][0], acc[0][0], 0, 0, 0);
      acc[1][0] = __builtin_amdgcn_mfma_f32_16x16x32_f16(al1, bh[k][0], acc[1][0], 0, 0, 0);
      acc[0][0] = __builtin_amdgcn_mfma_f32_16x16x32_f16(ah0, bl[k][0], acc[0][0], 0, 0, 0);
      acc[1][0] = __builtin_amdgcn_mfma_f32_16x16x32_f16(ah1, bl[k][0], acc[1][0], 0, 0, 0);
      if (two) {
        acc[0][1] = __builtin_amdgcn_mfma_f32_16x16x32_f16(ah0, bh[k][1], acc[0][1], 0, 0, 0);
        acc[1][1] = __builtin_amdgcn_mfma_f32_16x16x32_f16(ah1, bh[k][1], acc[1][1], 0, 0, 0);
        acc[0][1] = __builtin_amdgcn_mfma_f32_16x16x32_f16(al0, bh[k][1], acc[0][1], 0, 0, 0);
        acc[1][1] = __builtin_amdgcn_mfma_f32_16x16x32_f16(al1, bh[k][1], acc[1][1], 0, 0, 0);
        acc[0][1] = __builtin_amdgcn_mfma_f32_16x16x32_f16(ah0, bl[k][1], acc[0][1], 0, 0, 0);
        acc[1][1] = __builtin_amdgcn_mfma_f32_16x16x32_f16(ah1, bl[k][1], acc[1][1], 0, 0, 0);
      }
    }
    __syncthreads();
  }

  const size_t part = (size_t)kh * H0ROWS;
#pragma unroll
  for (int tt = 0; tt < 2; ++tt) {
#pragma unroll
    for (int r = 0; r < 4; ++r) {
      int row = r0 + tt * 16 + q * 4 + r;
      float* o = h0p + part + (size_t)row * 112;
      o[t0 * 16 + m] = acc[tt][0][r];
      if (two) o[t1 * 16 + m] = acc[tt][1][r];
    }
  }
}

// ---------------------------------------------------------------------------
// tree_mfma: block takes NVEC consecutive 100-vectors -> log2(NVEC) levels -> 1 vector.
// SUMIN: input = two leaf partial buffers (stride 112), +be and relu at load.
// PROJ: final kernel also computes the 2 logits.
// ---------------------------------------------------------------------------
template <int NVEC, bool PROJ, bool SUMIN>
__global__ __launch_bounds__(256, 1) void tree_mfma(const float* __restrict__ in,
                                                    float* __restrict__ out,
                                                    const half8* __restrict__ Wf,
                                                    const float* __restrict__ bt,
                                                    const float* __restrict__ be,
                                                    const float* __restrict__ Wp,
                                                    const float* __restrict__ bp) {
  __shared__ __align__(16) float bufA[16 * 228];
  __shared__ __align__(16) float bufB[16 * 228];
  const int tid = threadIdx.x;
  const int lane = tid & 63;
  const int wave = tid >> 6;
  const int q = lane >> 4, m = lane & 15;
  const int t0 = 2 * wave;
  const int t1 = (2 * wave + 1 > 6) ? 6 : 2 * wave + 1;

  half8 wh0[7], wl0[7], wh1[7], wl1[7];
#pragma unroll
  for (int ks = 0; ks < 7; ++ks) {
    wh0[ks] = Wf[(size_t)(ks * 14 + t0 * 2) * 64 + lane];
    wl0[ks] = Wf[(size_t)(ks * 14 + t0 * 2 + 1) * 64 + lane];
    wh1[ks] = Wf[(size_t)(ks * 14 + t1 * 2) * 64 + lane];
    wl1[ks] = Wf[(size_t)(ks * 14 + t1 * 2 + 1) * 64 + lane];
  }
  const int c0 = t0 * 16 + m;
  const int c1 = t1 * 16 + m;
  const float b0 = (c0 < 100) ? bt[c0] : 0.f;
  const float b1 = (c1 < 100) ? bt[c1] : 0.f;

  for (int i = tid; i < 16 * 228; i += 256) { bufA[i] = 0.f; bufB[i] = 0.f; }
  __syncthreads();
  if (SUMIN) {
    const size_t gb = (size_t)blockIdx.x * NVEC * 112;
    for (int i = tid; i < NVEC * 100; i += 256) {
      int v = i / 100, j = i - v * 100;
      float x = fmaxf(in[gb + (size_t)v * 112 + j] + in[H0ROWS + gb + (size_t)v * 112 + j] + be[j], 0.f);
      bufA[(v >> 1) * 228 + (v & 1) * 100 + j] = x;
    }
  } else {
    const float* gin = in + (size_t)blockIdx.x * NVEC * 100;
    for (int i = tid; i < NVEC * 100; i += 256) {
      int v = i / 100, j = i - v * 100;
      bufA[(v >> 1) * 228 + (v & 1) * 100 + j] = gin[i];
    }
  }
  __syncthreads();

  float* src = bufA;
  float* dst = bufB;
  constexpr int L = (NVEC == 32) ? 5 : 3;
#pragma unroll
  for (int l = 0; l < L; ++l) {
    const int nout = NVEC >> (l + 1);
    floatx4 acc0 = (floatx4){0.f, 0.f, 0.f, 0.f};
    floatx4 acc1 = (floatx4){0.f, 0.f, 0.f, 0.f};
#pragma unroll
    for (int ks = 0; ks < 7; ++ks) {
      const float* ap = src + m * 228 + ks * 32 + q * 8;
      floatx4 x0 = *(const floatx4*)ap;
      floatx4 x1 = *(const floatx4*)(ap + 4);
      half8 ah, al;
      cvt_hilo(x0, x1, ah, al);
      acc0 = __builtin_amdgcn_mfma_f32_16x16x32_f16(ah, wh0[ks], acc0, 0, 0, 0);
      acc1 = __builtin_amdgcn_mfma_f32_16x16x32_f16(ah, wh1[ks], acc1, 0, 0, 0);
      acc0 = __builtin_amdgcn_mfma_f32_16x16x32_f16(al, wh0[ks], acc0, 0, 0, 0);
      acc1 = __builtin_amdgcn_mfma_f32_16x16x32_f16(al, wh1[ks], acc1, 0, 0, 0);
      acc0 = __builtin_amdgcn_mfma_f32_16x16x32_f16(ah, wl0[ks], acc0, 0, 0, 0);
      acc1 = __builtin_amdgcn_mfma_f32_16x16x32_f16(ah, wl1[ks], acc1, 0, 0, 0);
    }
#pragma unroll
    for (int r = 0; r < 4; ++r) {
      int rowR = q * 4 + r;
      if (rowR < nout) {
        if (c0 < 100)
          dst[(rowR >> 1) * 228 + (rowR & 1) * 100 + c0] = fmaxf(acc0[r] + b0, 0.f);
        if (t1 != t0 && c1 < 100)
          dst[(rowR >> 1) * 228 + (rowR & 1) * 100 + c1] = fmaxf(acc1[r] + b1, 0.f);
      }
    }
    __syncthreads();
    float* tmp = src; src = dst; dst = tmp;
  }
  if (PROJ) {
    if (tid < 128) {
      int cls = tid >> 6, l = tid & 63;
      float sum = Wp[cls * 100 + l] * src[l];
      if (l + 64 < 100) sum += Wp[cls * 100 + l + 64] * src[l + 64];
#pragma unroll
      for (int off = 32; off > 0; off >>= 1) sum += __shfl_down(sum, off, 64);
      if (l == 0) out[cls] = sum + bp[cls];
    }
  } else {
    if (tid < 100) out[(size_t)blockIdx.x * 100 + tid] = src[tid];
  }
}

extern "C" void kernel_launch(void* const* d_in, const int* in_sizes, int n_in,
                              void* d_out, int out_size, void* d_ws, size_t ws_size,
                              hipStream_t stream) {
  (void)in_sizes; (void)n_in; (void)out_size; (void)ws_size;
  const float* leaf = (const float*)d_in[0];  // [8192][4096]
  const float* We = (const float*)d_in[1];    // [100][4096]
  const float* be = (const float*)d_in[2];    // [100]
  const float* W = (const float*)d_in[3];     // [100][200]
  const float* b = (const float*)d_in[4];     // [100]
  const float* Wp = (const float*)d_in[5];    // [2][100]
  const float* bp = (const float*)d_in[6];    // [2]
  float* out = (float*)d_out;                 // [2]

  char* ws = (char*)d_ws;
  half_t* Bf = (half_t*)ws;                        // 1792 frags * 1 KB
  half_t* Wfr = (half_t*)(ws + 1835008);           // 98 frags * 1 KB
  float* h0p = (float*)(ws + 1935360);             // 2 x 8192 x 112 fp32
  float* h1 = (float*)(ws + 9275392);              // 256*100*4
  float* h2 = (float*)(ws + 9377792);              // 8*100*4

  // Pipeline enqueued TWICE (idempotent) — differential-timing probe:
  // X (our controllable time) = dur_R6 - dur_R5; F (fixed window cost) = 2*dur_R5 - dur_R6.
  for (int rep = 0; rep < 2; ++rep) {
    prep<<<dim3(213), dim3(256), 0, stream>>>(We, W, Bf, Wfr);
    leaf_mfma<<<dim3(512), dim3(256), 0, stream>>>(leaf, (const half8*)Bf, h0p);
    tree_mfma<32, false, true><<<dim3(256), dim3(256), 0, stream>>>(h0p, h1, (const half8*)Wfr, b, be, nullptr, nullptr);
    tree_mfma<32, false, false><<<dim3(8), dim3(256), 0, stream>>>(h1, h2, (const half8*)Wfr, b, nullptr, nullptr, nullptr);
    tree_mfma<8, true, false><<<dim3(1), dim3(256), 0, stream>>>(h2, out, (const half8*)Wfr, b, nullptr, Wp, bp);
  }
}